// Round 1
// baseline (78.726 us; speedup 1.0000x reference)
//
#include <hip/hip_runtime.h>
#include <hip/hip_bf16.h>

// MyDeConv1D: dilated transposed-conv scatter, recast as GEMM + epilogue.
// out[b,t,f] = sum_{j=0..7,c} x[b, t+28-4j, c] * W[c,j,f]  (rows >= T are zero)
//            + cnt(t) * 256 * bias[f]
// GEMM shape: M=B*T=32768, N=F=256, K=C*KT=2048 -> bf16 MFMA 16x16x32.

#define B_    16
#define T_    2048
#define C_    256
#define KT    8
#define F_    256
#define DILL  4
#define SH    28          // (KT-1)*DILL
#define BT    64          // t-rows per block
#define ROWS  (BT + SH)   // 92 staged x rows

typedef __attribute__((ext_vector_type(8))) short short8;
typedef __attribute__((ext_vector_type(4))) float floatx4;

// W[c][j][f] f32  ->  Wt[j][f][c] bf16  (so B-frags are 16B-contiguous in c)
__global__ __launch_bounds__(256) void wprep_kernel(const float* __restrict__ W,
                                                    ushort* __restrict__ Wt) {
    int o = blockIdx.x * 256 + threadIdx.x;    // o = (j*256 + f)*256 + c
    int c = o & 255, f = (o >> 8) & 255, j = o >> 16;
    __hip_bfloat16 h = __float2bfloat16(W[(c * KT + j) * F_ + f]);
    Wt[o] = *reinterpret_cast<const ushort*>(&h);
}

__global__ __launch_bounds__(256, 2) void deconv_kernel(
        const float* __restrict__ x, const ushort* __restrict__ Wt,
        const float* __restrict__ bias, float* __restrict__ out) {
    __shared__ ushort xs[ROWS * C_];           // 92*256 bf16 = 47 KiB
    const int t0  = blockIdx.x * BT;
    const int b   = blockIdx.y;
    const int tid = threadIdx.x;

    // ---- stage x[t0 .. t0+ROWS) -> bf16 LDS, 16B chunks XOR-swizzled by row ----
    for (int idx = tid; idx < ROWS * 32; idx += 256) {
        const int row = idx >> 5, cb = idx & 31;
        const int t = t0 + row;
        float v[8] = {0.f,0.f,0.f,0.f,0.f,0.f,0.f,0.f};
        if (t < T_) {
            const float4* p = reinterpret_cast<const float4*>(
                x + ((b * T_ + t) * C_ + cb * 8));
            float4 u0 = p[0], u1 = p[1];
            v[0]=u0.x; v[1]=u0.y; v[2]=u0.z; v[3]=u0.w;
            v[4]=u1.x; v[5]=u1.y; v[6]=u1.z; v[7]=u1.w;
        }
        short8 pk;
        #pragma unroll
        for (int i = 0; i < 8; ++i) {
            __hip_bfloat16 h = __float2bfloat16(v[i]);
            pk[i] = *reinterpret_cast<const short*>(&h);
        }
        const int sc = cb ^ (row & 7);
        *reinterpret_cast<short8*>(&xs[row * C_ + sc * 8]) = pk;
    }
    __syncthreads();

    const int lane = tid & 63, wave = tid >> 6;
    const int l16 = lane & 15, q = lane >> 4;

    floatx4 acc[4][4];
    #pragma unroll
    for (int mf = 0; mf < 4; ++mf)
        #pragma unroll
        for (int nf = 0; nf < 4; ++nf)
            acc[mf][nf] = (floatx4){0.f, 0.f, 0.f, 0.f};

    for (int j = 0; j < KT; ++j) {
        const int shift = SH - DILL * j;       // 28,24,...,0
        #pragma unroll
        for (int cs = 0; cs < 8; ++cs) {       // K-step of 32 channels
            short8 a[4], bb[4];
            #pragma unroll
            for (int mf = 0; mf < 4; ++mf) {
                const int row   = mf * 16 + l16 + shift;          // < ROWS
                const int chunk = (cs * 4 + q) ^ (row & 7);
                a[mf] = *reinterpret_cast<const short8*>(&xs[row * C_ + chunk * 8]);
            }
            const int c0 = cs * 32 + q * 8;
            #pragma unroll
            for (int nf = 0; nf < 4; ++nf) {
                const int f = (wave * 4 + nf) * 16 + l16;
                bb[nf] = *reinterpret_cast<const short8*>(&Wt[(j * F_ + f) * C_ + c0]);
            }
            #pragma unroll
            for (int mf = 0; mf < 4; ++mf)
                #pragma unroll
                for (int nf = 0; nf < 4; ++nf)
                    acc[mf][nf] = __builtin_amdgcn_mfma_f32_16x16x32_bf16(
                        a[mf], bb[nf], acc[mf][nf], 0, 0, 0);
        }
    }

    // ---- epilogue: + cnt(t) * C * bias[f];  C/D map row=(q*4+r), col=l16 ----
    #pragma unroll
    for (int nf = 0; nf < 4; ++nf) {
        const int f  = (wave * 4 + nf) * 16 + l16;
        const float bf = bias[f];
        #pragma unroll
        for (int mf = 0; mf < 4; ++mf) {
            #pragma unroll
            for (int r = 0; r < 4; ++r) {
                const int t = t0 + mf * 16 + q * 4 + r;
                const int jmin = (t <= T_ - SH - 1) ? 0 : (((t - (T_ - SH)) >> 2) + 1);
                out[(b * T_ + t) * F_ + f] = acc[mf][nf][r] + (float)(8 - jmin) * 256.0f * bf;
            }
        }
    }
}

extern "C" void kernel_launch(void* const* d_in, const int* in_sizes, int n_in,
                              void* d_out, int out_size, void* d_ws, size_t ws_size,
                              hipStream_t stream) {
    const float* x    = (const float*)d_in[0];
    const float* W    = (const float*)d_in[1];   // (C,KT,F)
    const float* bias = (const float*)d_in[2];
    float* out = (float*)d_out;
    ushort* Wt = (ushort*)d_ws;                  // KT*F*C bf16 = 1 MiB scratch

    wprep_kernel<<<(KT * F_ * C_) / 256, 256, 0, stream>>>(W, Wt);
    dim3 grid(T_ / BT, B_);
    deconv_kernel<<<grid, 256, 0, stream>>>(x, Wt, bias, out);
}

// Round 2
// 48.039 us; speedup vs baseline: 1.6388x; 1.6388x over previous
//
#include <hip/hip_runtime.h>
#include <hip/hip_bf16.h>

// MyDeConv1D: dilated transposed-conv scatter, recast as GEMM + epilogue.
// out[b,t,f] = sum_{j=0..7,c} x[b, t+28-4j, c] * W[c,j,f]  (rows >= T are zero)
//            + cnt(t) * 256 * bias[f]
// GEMM shape: M=B*T=32768, N=F=256, K=C*KT=2048 -> bf16 MFMA 16x16x32.
// R2: W pre-permuted to per-fragment coalesced order (1KB/frag, one txn) +
//     explicit 2-deep software pipeline in the barrier-free K-loop.

#define B_    16
#define T_    2048
#define C_    256
#define KT    8
#define F_    256
#define DILL  4
#define SH    28          // (KT-1)*DILL
#define BT    64          // t-rows per block
#define ROWS  (BT + SH)   // 92 staged x rows

typedef __attribute__((ext_vector_type(8))) short short8;
typedef __attribute__((ext_vector_type(4))) float floatx4;

// W[c][j][f] f32 -> Wf[((j*8+cs)*16+g)][lane][i] bf16.
// Fragment (j,cs,g): lane holds B[k=q*8+i][n=l16] for f=g*16+l16, c=cs*32+q*8+i.
// Each fragment is 64 lanes * 16B = 1KB contiguous -> one coalesced load.
__global__ __launch_bounds__(256) void wprep_kernel(const float* __restrict__ W,
                                                    ushort* __restrict__ Wf) {
    const int o    = blockIdx.x * 256 + threadIdx.x;
    const int i    = o & 7;
    const int lane = (o >> 3) & 63;
    const int g    = (o >> 9) & 15;
    const int cs   = (o >> 13) & 7;
    const int j    = o >> 16;
    const int c    = cs * 32 + (lane >> 4) * 8 + i;
    const int f    = g * 16 + (lane & 15);
    __hip_bfloat16 h = __float2bfloat16(W[(c * KT + j) * F_ + f]);
    Wf[o] = *reinterpret_cast<const ushort*>(&h);
}

__global__ __launch_bounds__(256, 2) void deconv_kernel(
        const float* __restrict__ x, const ushort* __restrict__ Wf,
        const float* __restrict__ bias, float* __restrict__ out) {
    __shared__ ushort xs[ROWS * C_];           // 92*256 bf16 = 47 KiB
    const int t0  = blockIdx.x * BT;
    const int b   = blockIdx.y;
    const int tid = threadIdx.x;

    // ---- stage x[t0 .. t0+ROWS) -> bf16 LDS, 16B chunks XOR-swizzled by row ----
    for (int idx = tid; idx < ROWS * 32; idx += 256) {
        const int row = idx >> 5, cb = idx & 31;
        const int t = t0 + row;
        float v[8] = {0.f,0.f,0.f,0.f,0.f,0.f,0.f,0.f};
        if (t < T_) {
            const float4* p = reinterpret_cast<const float4*>(
                x + ((b * T_ + t) * C_ + cb * 8));
            float4 u0 = p[0], u1 = p[1];
            v[0]=u0.x; v[1]=u0.y; v[2]=u0.z; v[3]=u0.w;
            v[4]=u1.x; v[5]=u1.y; v[6]=u1.z; v[7]=u1.w;
        }
        short8 pk;
        #pragma unroll
        for (int i = 0; i < 8; ++i) {
            __hip_bfloat16 h = __float2bfloat16(v[i]);
            pk[i] = *reinterpret_cast<const short*>(&h);
        }
        const int sc = cb ^ (row & 7);
        *reinterpret_cast<short8*>(&xs[row * C_ + sc * 8]) = pk;
    }

    const int lane = tid & 63, wave = tid >> 6;
    const int l16 = lane & 15, q = lane >> 4;

    // hoist bias (global, hide under K-loop)
    float bf4[4];
    #pragma unroll
    for (int nf = 0; nf < 4; ++nf) bf4[nf] = bias[(wave * 4 + nf) * 16 + l16];

    __syncthreads();

    floatx4 acc[4][4];
    #pragma unroll
    for (int mf = 0; mf < 4; ++mf)
        #pragma unroll
        for (int nf = 0; nf < 4; ++nf)
            acc[mf][nf] = (floatx4){0.f, 0.f, 0.f, 0.f};

    const ushort* wbase = Wf + wave * 2048 + lane * 8;   // + s*8192 + nf*512

#define LOAD_A(s_, arr) do {                                              \
        const int j_ = (s_) >> 3, cs_ = (s_) & 7;                         \
        const int shift_ = SH - 4 * j_;                                   \
        _Pragma("unroll")                                                 \
        for (int mf = 0; mf < 4; ++mf) {                                  \
            const int row_ = mf * 16 + l16 + shift_;                      \
            const int ch_  = ((cs_ << 2) + q) ^ (row_ & 7);               \
            arr[mf] = *reinterpret_cast<const short8*>(                   \
                &xs[row_ * C_ + ch_ * 8]);                                \
        } } while (0)

#define LOAD_B(s_, arr) do {                                              \
        const ushort* p_ = wbase + (s_) * 8192;                           \
        _Pragma("unroll")                                                 \
        for (int nf = 0; nf < 4; ++nf)                                    \
            arr[nf] = *reinterpret_cast<const short8*>(p_ + nf * 512);    \
        } while (0)

#define DO_MFMA(aa, bb) do {                                              \
        _Pragma("unroll")                                                 \
        for (int mf = 0; mf < 4; ++mf)                                    \
            _Pragma("unroll")                                             \
            for (int nf = 0; nf < 4; ++nf)                                \
                acc[mf][nf] = __builtin_amdgcn_mfma_f32_16x16x32_bf16(    \
                    aa[mf], bb[nf], acc[mf][nf], 0, 0, 0);                \
        } while (0)

    short8 a0[4], b0[4], a1[4], b1[4];
    LOAD_A(0, a0); LOAD_B(0, b0);
    LOAD_A(1, a1); LOAD_B(1, b1);

    for (int s = 0; s < 64; s += 2) {
        DO_MFMA(a0, b0);
        const int sp2 = (s + 2) & 63;        // wraps harmlessly on last iter
        LOAD_A(sp2, a0); LOAD_B(sp2, b0);
        DO_MFMA(a1, b1);
        const int sp3 = (s + 3) & 63;
        LOAD_A(sp3, a1); LOAD_B(sp3, b1);
    }

    // ---- epilogue: + cnt(t) * C * bias[f];  C/D map row=(q*4+r), col=l16 ----
    #pragma unroll
    for (int nf = 0; nf < 4; ++nf) {
        const int f = (wave * 4 + nf) * 16 + l16;
        #pragma unroll
        for (int mf = 0; mf < 4; ++mf) {
            #pragma unroll
            for (int r = 0; r < 4; ++r) {
                const int t = t0 + mf * 16 + q * 4 + r;
                const int jmin = (t < T_ - SH) ? 0 : (((t - (T_ - SH)) >> 2) + 1);
                out[(b * T_ + t) * F_ + f] =
                    acc[mf][nf][r] + (float)(8 - jmin) * 256.0f * bf4[nf];
            }
        }
    }
#undef LOAD_A
#undef LOAD_B
#undef DO_MFMA
}

extern "C" void kernel_launch(void* const* d_in, const int* in_sizes, int n_in,
                              void* d_out, int out_size, void* d_ws, size_t ws_size,
                              hipStream_t stream) {
    const float* x    = (const float*)d_in[0];
    const float* W    = (const float*)d_in[1];   // (C,KT,F)
    const float* bias = (const float*)d_in[2];
    float* out = (float*)d_out;
    ushort* Wf = (ushort*)d_ws;                  // KT*F*C bf16 = 1 MiB scratch

    wprep_kernel<<<(KT * F_ * C_) / 256, 256, 0, stream>>>(W, Wf);
    dim3 grid(T_ / BT, B_);
    deconv_kernel<<<grid, 256, 0, stream>>>(x, Wf, bias, out);
}